// Round 11
// baseline (1174.009 us; speedup 1.0000x reference)
//
#include <hip/hip_runtime.h>
#include <stdint.h>

typedef unsigned char u8;
typedef unsigned short u16;
typedef uint32_t u32;

#define NTOT 4096
#define SS   32
#define DD   128
#define EPSK 1e-6f
#define NITER 20
#define CAPC 4460544u      // max nt*roundup(nc,128) over all splits with nt,nc<=2304
#define LDC_FIT 2304       // LDS-resident z/w limit (nt,nc=2048±8sigma safe)
#define WSTR 2432          // per-ts vector stride (floats)
#define SU_OFF 2308
#define UNT_OFF 2309
#define BPT 32             // blocks per ts: k_iter (4 blocks/CU after zl/watw LDS union)
#define BPTF 64            // blocks per ts: k_fin

typedef __attribute__((ext_vector_type(8))) short short8;
typedef __attribute__((ext_vector_type(4))) float f32x4;
typedef __attribute__((ext_vector_type(2))) float f32x2;

__device__ __forceinline__ float bf2f(u16 h){ return __uint_as_float(((u32)h) << 16); }
__device__ __forceinline__ u16 f2bf(float f){
  u32 u = __float_as_uint(f);
  u += 0x7fffu + ((u >> 16) & 1u);
  return (u16)(u >> 16);
}
// column permutation within each 64-col group: col j*16+r  <->  stored r*4+j
__device__ __forceinline__ int invpermc(int cp){
  return (cp & ~63) | ((cp & 3) << 4) | ((cp >> 2) & 15);
}
__device__ __forceinline__ uint4 u4zero(){ uint4 t; t.x=0u; t.y=0u; t.z=0u; t.w=0u; return t; }

// ---------------- compact treated/control index lists --------------------------------
__global__ __launch_bounds__(1024) void k_compact(const int* __restrict__ t,
    int* __restrict__ itidx, int* __restrict__ icidx, int* __restrict__ meta,
    float* __restrict__ fmeta)
{
  __shared__ int sc[1024];
  int tid = threadIdx.x;
  int e0 = tid * 4;
  int tv[4]; int c = 0;
  #pragma unroll
  for (int e = 0; e < 4; e++){ tv[e] = t[e0 + e]; c += (tv[e] > 0) ? 1 : 0; }
  sc[tid] = c;
  __syncthreads();
  for (int off = 1; off < 1024; off <<= 1){
    int v = sc[tid];
    int add = (tid >= off) ? sc[tid - off] : 0;
    __syncthreads();
    sc[tid] = v + add;
    __syncthreads();
  }
  int incl = sc[tid];
  int excl = incl - c;
  int oT = excl, oC = e0 - excl;
  #pragma unroll
  for (int e = 0; e < 4; e++){
    if (tv[e] > 0) itidx[oT++] = e0 + e;
    else           icidx[oC++] = e0 + e;
  }
  if (tid == 1023){
    meta[0] = incl; meta[1] = NTOT - incl;
    fmeta[0] = (float)incl / (float)NTOT;
  }
}

__global__ void k_zero(float* __restrict__ p, int n)
{
  int i = blockIdx.x * 256 + threadIdx.x;
  if (i < n) p[i] = 0.f;
}

// ---------------- init w-slot-0 scalars -----------------------------------------------
__global__ void k_vinit(const float* __restrict__ fmeta, float* __restrict__ w0)
{
  if (threadIdx.x == 0){
    float p = fmeta[0];
    float* w = w0 + (size_t)blockIdx.x * WSTR;
    w[SU_OFF]  = p;
    w[UNT_OFF] = 1.0f - p;
  }
}

// ---------------- gather X -> bf16 Xt/Xc + row norms ----------------------------------
// R14 rewrite: ONE float4 per thread (8 rows x 32 f4-cols per block), norm via
// 32-lane-group shfl tree. Full TLP, coalesced.
__global__ __launch_bounds__(256) void k_pack(const float* __restrict__ X,
    const int* __restrict__ itidx, const int* __restrict__ icidx,
    const int* __restrict__ meta, u16* __restrict__ XT, u16* __restrict__ XC,
    float* __restrict__ nxT, float* __restrict__ nxC, int ts0)
{
  int isC = blockIdx.y;
  int z = blockIdx.z;
  int s = ts0 + z;
  int n = isC ? meta[1] : meta[0];
  int lane32 = threadIdx.x & 31;                 // f4-column within row
  int r = blockIdx.x * 8 + (threadIdx.x >> 5);   // 8 rows per block
  if (r >= n) return;                            // uniform within each 32-lane group
  int idx = isC ? icidx[r] : itidx[r];
  const float4* src = (const float4*)(X + ((size_t)idx * SS + s) * DD);
  float4 v = src[lane32];
  float pn = v.x*v.x + v.y*v.y + v.z*v.z + v.w*v.w;
  u32 lo = (u32)f2bf(v.x) | ((u32)f2bf(v.y) << 16);
  u32 hi = (u32)f2bf(v.z) | ((u32)f2bf(v.w) << 16);
  uint2 pk; pk.x = lo; pk.y = hi;
  u16* dst = (isC ? XC : XT) + ((size_t)z * NTOT + r) * DD;
  ((uint2*)dst)[lane32] = pk;
  #pragma unroll
  for (int o = 16; o; o >>= 1) pn += __shfl_xor(pn, o, 32);
  if (lane32 == 0) (isC ? nxC : nxT)[z * NTOT + r] = pn;
}

// ---------------- per-ts column sums + norm sums (for analytic mean(M)) ---------------
__global__ __launch_bounds__(256) void k_stats(const u16* __restrict__ XT,
    const u16* __restrict__ XC, const float* __restrict__ nxT, const float* __restrict__ nxC,
    const int* __restrict__ meta, float* __restrict__ gsx, float* __restrict__ gsn)
{
  int side = blockIdx.y, z = blockIdx.z;
  int n = side ? meta[1] : meta[0];
  int chunk = (n + 7) >> 3;
  int r0 = blockIdx.x * chunk;
  int r1 = min(r0 + chunk, n);
  const u16* B = (side ? XC : XT) + (size_t)z * NTOT * DD;
  int tid = threadIdx.x;
  int d = tid & 127, half = tid >> 7;
  float sx = 0.f;
  for (int r = r0 + half; r < r1; r += 2) sx += bf2f(B[(size_t)r * DD + d]);
  __shared__ float sp[256];
  sp[tid] = sx;
  __syncthreads();
  if (tid < 128) unsafeAtomicAdd(&gsx[(size_t)(z*2+side)*128 + tid], sp[tid] + sp[tid+128]);
  const float* nrm = (side ? nxC : nxT) + (size_t)z * NTOT;
  float sn = 0.f;
  for (int r = r0 + tid; r < r1; r += 256) sn += nrm[r];
  #pragma unroll
  for (int o = 32; o; o >>= 1) sn += __shfl_xor(sn, o);
  __syncthreads();
  if ((tid & 63) == 0) sp[tid >> 6] = sn;
  __syncthreads();
  if (tid == 0) unsafeAtomicAdd(&gsn[z*2+side], sp[0]+sp[1]+sp[2]+sp[3]);
}

// ---------------- lam = nt*nc/sum(M) analytically --------------------------------------
__global__ void k_lam(const float* __restrict__ gsx, const float* __restrict__ gsn,
                      const int* __restrict__ meta, float* __restrict__ stats)
{
  int z = blockIdx.x, tid = threadIdx.x;  // 128 threads
  float d = gsx[(size_t)(z*2)*128 + tid] * gsx[(size_t)(z*2+1)*128 + tid];
  #pragma unroll
  for (int o = 32; o; o >>= 1) d += __shfl_xor(d, o);
  __shared__ float rr[2];
  if ((tid & 63) == 0) rr[tid >> 6] = d;
  __syncthreads();
  if (tid == 0){
    float nt = (float)meta[0], nc = (float)meta[1];
    float msum = nc * gsn[z*2] + nt * gsn[z*2+1] - 2.f * (rr[0] + rr[1]);
    stats[z*8+0] = nt * nc / msum;   // lam
    stats[z*8+1] = msum / (nt * nc); // 1/lam = mean(M)
  }
}

// ---------------- GEMM: K = fp8(exp(-lam*M)) (HW cvt, permuted direct store) ----------
// R7/R8 (verified win, 285->160us): vmax atomicMax de-contended + kh reg double-buffer.
// R10 z0-split kept (surfaces sweep kernels in rocprof top-5; negligible cost).
#define LDA2 72
__global__ __launch_bounds__(256) void k_gemm(const u16* __restrict__ XT,
    const u16* __restrict__ XC, const float* __restrict__ nxT, const float* __restrict__ nxC,
    const int* __restrict__ meta, const float* __restrict__ fmeta,
    const float* __restrict__ stats, float* __restrict__ vmx,
    u8* __restrict__ Kc, float* __restrict__ w0base, int z0)
{
  int nt = meta[0], nc = meta[1];
  if (nt > LDC_FIT || nc > LDC_FIT) return;
  int bx = blockIdx.x, by = blockIdx.y, z = z0 + blockIdx.z;
  if (by * 128 >= nt || bx * 128 >= nc) return;
  __shared__ __align__(16) u16 As[128 * LDA2];
  __shared__ __align__(16) u16 Bs[128 * LDA2];
  __shared__ float watile[256];
  __shared__ float nxs[128];
  __shared__ float nys[128];
  __shared__ float vred[4];
  int tid = threadIdx.x;
  int wid = tid >> 6, lane = tid & 63;
  int wm = (wid >> 1) * 64, wn = (wid & 1) * 64;
  int lrow = lane & 15, lquad = lane >> 4;

  float lam = stats[z*8+0];     // hoisted: stats line is read-only during k_gemm now

  // stage this block's row/col norms into LDS (coalesced, once)
  if (tid < 128){
    int gi = by*128 + tid;
    nxs[tid] = (gi < nt) ? nxT[(size_t)z * NTOT + gi] : 0.f;
  } else {
    int gj = bx*128 + (tid - 128);
    nys[tid - 128] = (gj < nc) ? nxC[(size_t)z * NTOT + gj] : 0.f;
  }

  f32x4 acc[4][4];
  #pragma unroll
  for (int i = 0; i < 4; i++){
    #pragma unroll
    for (int j = 0; j < 4; j++){
      acc[i][j][0]=0.f; acc[i][j][1]=0.f; acc[i][j][2]=0.f; acc[i][j][3]=0.f;
    }
  }

  int r = tid & 127;
  int isB = tid >> 7;
  int g = (isB ? bx : by) * 128 + r;
  int lim = isB ? nc : nt;
  const u16* srcbase = (isB ? XC : XT) + ((size_t)z * NTOT + g) * DD;
  u16* dl = (isB ? Bs : As) + r * LDA2;

  auto mmstep = [&](){
    #pragma unroll
    for (int ks = 0; ks < 2; ks++){
      int koff = ks * 32 + lquad * 8;
      short8 af[4], bfr[4];
      #pragma unroll
      for (int i = 0; i < 4; i++) af[i]  = *(const short8*)(As + (wm + i*16 + lrow) * LDA2 + koff);
      #pragma unroll
      for (int j = 0; j < 4; j++) bfr[j] = *(const short8*)(Bs + (wn + j*16 + lrow) * LDA2 + koff);
      #pragma unroll
      for (int i = 0; i < 4; i++){
        #pragma unroll
        for (int j = 0; j < 4; j++){
          acc[i][j] = __builtin_amdgcn_mfma_f32_16x16x32_bf16(af[i], bfr[j], acc[i][j], 0, 0, 0);
        }
      }
    }
  };

  // stage kh=0 (regs -> LDS)
  uint4 st[8];
  if (g < lim){
    const uint4* src = (const uint4*)(srcbase);
    #pragma unroll
    for (int q = 0; q < 8; q++) st[q] = src[q];
  } else {
    #pragma unroll
    for (int q = 0; q < 8; q++) st[q] = u4zero();
  }
  #pragma unroll
  for (int q = 0; q < 8; q++) ((uint4*)dl)[q] = st[q];
  __syncthreads();

  // prefetch kh=1 into regs (overlaps kh=0 MFMAs)
  if (g < lim){
    const uint4* src = (const uint4*)(srcbase + 64);
    #pragma unroll
    for (int q = 0; q < 8; q++) st[q] = src[q];
  } else {
    #pragma unroll
    for (int q = 0; q < 8; q++) st[q] = u4zero();
  }

  mmstep();                 // kh=0
  __syncthreads();
  #pragma unroll
  for (int q = 0; q < 8; q++) ((uint4*)dl)[q] = st[q];
  __syncthreads();
  mmstep();                 // kh=1

  // ---- epilogue: exp -> HW fp8 pack -> permuted coalesced u32 stores ----
  int ldc = (nc + 127) & ~127;
  float p = fmeta[0];
  float a0 = p / (float)nt;
  u8* Kz = Kc + (size_t)z * CAPC;

  float nyv[4]; bool jin[4];
  #pragma unroll
  for (int j = 0; j < 4; j++){
    int lcol = wn + j*16 + lrow;
    jin[j] = (bx*128 + lcol) < nc;
    nyv[j] = nys[lcol];
  }
  float vmax = 0.f;
  float colsum[4] = {0.f, 0.f, 0.f, 0.f};
  size_t cbase = (size_t)(bx*128 + wn + lrow*4);
  #pragma unroll
  for (int i = 0; i < 4; i++){
    #pragma unroll
    for (int rr2 = 0; rr2 < 4; rr2++){
      int lr = wm + i*16 + lquad*4 + rr2;
      int gi = by*128 + lr;
      bool iin = gi < nt;
      float nxv = nxs[lr];
      float cv[4];
      #pragma unroll
      for (int j = 0; j < 4; j++){
        float m = nxv + nyv[j] - 2.0f * acc[i][j][rr2];
        cv[j] = __expf(-lam * m);
        if (iin && jin[j]){ vmax = fmaxf(vmax, m); colsum[j] += cv[j]; }
      }
      u32 pk = (u32)__builtin_amdgcn_cvt_pk_fp8_f32(cv[0], cv[1], 0, false);
      pk = (u32)__builtin_amdgcn_cvt_pk_fp8_f32(cv[2], cv[3], (int)pk, true);
      if (iin) *(u32*)(Kz + (size_t)gi * ldc + cbase) = pk;
    }
  }
  // merge colsum over the 4 quads of this wave
  #pragma unroll
  for (int j = 0; j < 4; j++){
    colsum[j] += __shfl_xor(colsum[j], 16);
    colsum[j] += __shfl_xor(colsum[j], 32);
  }
  if (lane < 16){
    #pragma unroll
    for (int j = 0; j < 4; j++) watile[wid * 64 + j*16 + lrow] = colsum[j];
  }
  #pragma unroll
  for (int o = 32; o; o >>= 1) vmax = fmaxf(vmax, __shfl_xor(vmax, o));
  if (lane == 0) vred[wid] = vmax;
  __syncthreads();
  if (tid == 0){
    float vm = fmaxf(fmaxf(vred[0], vred[1]), fmaxf(vred[2], vred[3]));
    atomicMax((int*)(vmx + (size_t)z*32), __float_as_int(vm));
  }
  // w0 = (p/nt) * column sums
  if (tid < 128){
    int gj = bx*128 + tid;
    if (gj < nc){
      float v = (tid < 64) ? (watile[tid] + watile[128 + tid])
                           : (watile[64 + (tid-64)] + watile[192 + (tid-64)]);
      unsafeAtomicAdd(w0base + (size_t)z * WSTR + gj, v * a0);
    }
  }
}

// ---------------- fused Sinkhorn iteration: z(w) -> u' -> w' = K^T u' ------------------
// R15 counters: VGPR=112 at (256,2), no spill (WRITE_SIZE = just w' atomics). Scaling:
// 1 blk/CU=50us, 2 blk/CU=37us -> latency/TLP-bound, wants more blocks. LDS was the
// occupancy limiter (46.6KB -> 3/CU). R16: zl is DEAD after the zv-hoist -> union it
// with watw stripe 0 (barrier after hoist makes alias safe). LDS ~37KB -> 4 blocks/CU
// at (256,2) with NO launch_bounds change (R14's spill mechanism can't recur). BPT=32.
// HARD INVARIANT: never cap VGPR below 256 here ((256,3)/(256,4) -> scratch, R14: 6.8x).
__global__ __launch_bounds__(256, 2) void k_iter(const u8* __restrict__ Kc,
    const float* __restrict__ wprev, float* __restrict__ wnext,
    float* __restrict__ ubuf, const int* __restrict__ meta,
    const float* __restrict__ fmeta, const float* __restrict__ stats,
    const float* __restrict__ vmx, int writeU)
{
  __shared__ __align__(16) float watw[4 * LDC_FIT];
  __shared__ float red[4];
  float* zl = watw;              // alias: zl lives only until the zv-hoist barrier
  int nt = meta[0], nc = meta[1];
  if (nt > LDC_FIT || nc > LDC_FIT) return;
  int ldc = (nc + 127) & ~127;
  int z = blockIdx.y, b = blockIdx.x;
  int tid = threadIdx.x, wid = tid >> 6, lane = tid & 63;
  float p = fmeta[0];
  float b0 = (1.0f - p) / (float)nc;
  float a0 = p / (float)nt;
  float lam = stats[z*8+0];
  float delta = vmx[(size_t)z*32];
  float kc = __expf(-lam * delta);
  float kce = kc + EPSK;
  const float* wp = wprev + (size_t)z * WSTR;
  float* wnx = wnext + (size_t)z * WSTR;
  float SU = wp[SU_OFF], UNT = wp[UNT_OFF];
  float wext = EPSK * (SU + UNT) + kc * UNT;
  float wnc = kce * SU + (1.0f + EPSK) * UNT;
  float znc = p / wnc;

  // stage z into LDS in PERMUTED order
  float zp = 0.f;
  for (int cp = tid; cp < ldc; cp += 256){
    int c = invpermc(cp);
    float v = 0.f;
    if (c < nc) v = b0 * __builtin_amdgcn_rcpf(wp[c] + wext);
    zl[cp] = v;
    zp += v;
  }
  #pragma unroll
  for (int o = 32; o; o >>= 1) zp += __shfl_xor(zp, o);
  if (lane == 0) red[wid] = zp;
  __syncthreads();
  float Z = red[0] + red[1] + red[2] + red[3];
  float dotX = EPSK * Z + kce * znc;
  float untN = (1.0f - p) / (kce * Z + (1.0f + EPSK) * znc);

  // hoist this lane's 48 z values into registers (hot loop: no LDS)
  int cb0 = lane * 16;
  float zv[48];
  #pragma unroll
  for (int s = 0; s < 3; s++){
    int cb = s*1024 + cb0;
    if (cb < ldc){
      #pragma unroll
      for (int q = 0; q < 4; q++){
        float4 t4 = *(const float4*)(zl + cb + q*4);
        zv[s*16+q*4+0]=t4.x; zv[s*16+q*4+1]=t4.y; zv[s*16+q*4+2]=t4.z; zv[s*16+q*4+3]=t4.w;
      }
    } else {
      #pragma unroll
      for (int k = 0; k < 16; k++) zv[s*16+k] = 0.f;
    }
  }
  __syncthreads();   // zl dead after this point for ALL waves -> watw may overwrite it

  float wacc[48];
  #pragma unroll
  for (int k = 0; k < 48; k++) wacc[k] = 0.f;
  float rsum = 0.f;

  int nbx = gridDim.x;
  int rpb = (nt + nbx - 1) / nbx;
  int r0 = b * rpb, r1 = min(r0 + rpb, nt);
  const u8* Kz = Kc + (size_t)z * CAPC;
  bool c0ok = (cb0 < ldc), c1ok = (1024 + cb0 < ldc), c2ok = (2048 + cb0 < ldc);

  for (int r = r0 + wid*2; r < r1; r += 8){
    int rB = r + 1;
    bool bok = rB < r1;
    const u8* KrA = Kz + (size_t)r * ldc;
    uint4 qa0 = u4zero(), qa1 = u4zero(), qa2 = u4zero();
    uint4 qb0 = u4zero(), qb1 = u4zero(), qb2 = u4zero();
    if (c0ok) qa0 = *(const uint4*)(KrA + cb0);
    if (c1ok) qa1 = *(const uint4*)(KrA + 1024 + cb0);
    if (c2ok) qa2 = *(const uint4*)(KrA + 2048 + cb0);
    if (bok){
      const u8* KrB = Kz + (size_t)rB * ldc;
      if (c0ok) qb0 = *(const uint4*)(KrB + cb0);
      if (c1ok) qb1 = *(const uint4*)(KrB + 1024 + cb0);
      if (c2ok) qb2 = *(const uint4*)(KrB + 2048 + cb0);
    }
    u32 wdA[12] = {qa0.x, qa0.y, qa0.z, qa0.w,
                   qa1.x, qa1.y, qa1.z, qa1.w,
                   qa2.x, qa2.y, qa2.z, qa2.w};
    u32 wdB[12] = {qb0.x, qb0.y, qb0.z, qb0.w,
                   qb1.x, qb1.y, qb1.z, qb1.w,
                   qb2.x, qb2.y, qb2.z, qb2.w};
    // pass 1: decode -> dots (two independent chains)
    float d4A[4] = {0.f, 0.f, 0.f, 0.f};
    float d4B[4] = {0.f, 0.f, 0.f, 0.f};
    #pragma unroll
    for (int q = 0; q < 12; q++){
      f32x2 a0v = __builtin_amdgcn_cvt_pk_f32_fp8((int)wdA[q], false);
      f32x2 a1v = __builtin_amdgcn_cvt_pk_f32_fp8((int)wdA[q], true);
      d4A[0] = fmaf(a0v.x, zv[q*4+0], d4A[0]);
      d4A[1] = fmaf(a0v.y, zv[q*4+1], d4A[1]);
      d4A[2] = fmaf(a1v.x, zv[q*4+2], d4A[2]);
      d4A[3] = fmaf(a1v.y, zv[q*4+3], d4A[3]);
      f32x2 b0v = __builtin_amdgcn_cvt_pk_f32_fp8((int)wdB[q], false);
      f32x2 b1v = __builtin_amdgcn_cvt_pk_f32_fp8((int)wdB[q], true);
      d4B[0] = fmaf(b0v.x, zv[q*4+0], d4B[0]);
      d4B[1] = fmaf(b0v.y, zv[q*4+1], d4B[1]);
      d4B[2] = fmaf(b1v.x, zv[q*4+2], d4B[2]);
      d4B[3] = fmaf(b1v.y, zv[q*4+3], d4B[3]);
    }
    float dotA = (d4A[0] + d4A[1]) + (d4A[2] + d4A[3]);
    float dotB = (d4B[0] + d4B[1]) + (d4B[2] + d4B[3]);
    // interleaved 64-lane reduces: two chains hide each other's shuffle latency
    #pragma unroll
    for (int o = 32; o; o >>= 1){
      dotA += __shfl_xor(dotA, o);
      dotB += __shfl_xor(dotB, o);
    }
    float uvA = a0 * __builtin_amdgcn_rcpf(dotA + dotX);
    float uvB = bok ? (a0 * __builtin_amdgcn_rcpf(dotB + dotX)) : 0.f;
    rsum += uvA;
    rsum += uvB;
    if (writeU && lane == 0){
      ubuf[(size_t)z * WSTR + r] = uvA;
      if (bok) ubuf[(size_t)z * WSTR + rB] = uvB;
    }
    // pass 2: re-decode -> wacc (kd[48] eliminated; uvB=0 makes masked row a no-op)
    #pragma unroll
    for (int q = 0; q < 12; q++){
      f32x2 a0v = __builtin_amdgcn_cvt_pk_f32_fp8((int)wdA[q], false);
      f32x2 a1v = __builtin_amdgcn_cvt_pk_f32_fp8((int)wdA[q], true);
      wacc[q*4+0] = fmaf(a0v.x, uvA, wacc[q*4+0]);
      wacc[q*4+1] = fmaf(a0v.y, uvA, wacc[q*4+1]);
      wacc[q*4+2] = fmaf(a1v.x, uvA, wacc[q*4+2]);
      wacc[q*4+3] = fmaf(a1v.y, uvA, wacc[q*4+3]);
      f32x2 b0v = __builtin_amdgcn_cvt_pk_f32_fp8((int)wdB[q], false);
      f32x2 b1v = __builtin_amdgcn_cvt_pk_f32_fp8((int)wdB[q], true);
      wacc[q*4+0] = fmaf(b0v.x, uvB, wacc[q*4+0]);
      wacc[q*4+1] = fmaf(b0v.y, uvB, wacc[q*4+1]);
      wacc[q*4+2] = fmaf(b1v.x, uvB, wacc[q*4+2]);
      wacc[q*4+3] = fmaf(b1v.y, uvB, wacc[q*4+3]);
    }
  }
  // per-wave private LDS copy, then merged global atomic (unpermute here)
  #pragma unroll
  for (int s = 0; s < 3; s++){
    int cb = s*1024 + cb0;
    if (cb < ldc){
      #pragma unroll
      for (int q = 0; q < 4; q++)
        *(float4*)(watw + (size_t)wid * LDC_FIT + cb + q*4) =
            make_float4(wacc[s*16+q*4+0], wacc[s*16+q*4+1], wacc[s*16+q*4+2], wacc[s*16+q*4+3]);
    }
  }
  if (lane == 0) unsafeAtomicAdd(wnx + SU_OFF, rsum);
  if (b == 0 && tid == 0) wnx[UNT_OFF] = untN;
  __syncthreads();
  for (int cp = tid; cp < ldc; cp += 256){
    int c = invpermc(cp);
    if (c < nc){
      float v = watw[cp] + watw[LDC_FIT + cp] + watw[2*LDC_FIT + cp] + watw[3*LDC_FIT + cp];
      unsafeAtomicAdd(wnx + c, v);
    }
  }
}

// ---------------- final: tsacc += sum(T * Mt), M recovered via -log(K)/lam -------------
// R13 LUT (verified: k_fin 88 -> <70): fp8 -> (v+eps)*log(max(v,1e-4)) in LDS, inner
// loop = bfe + ds_read + fma. 4 staggered replicas (264-float stride).
__global__ __launch_bounds__(256, 2) void k_fin(const u8* __restrict__ Kc,
    const float* __restrict__ wprev, const float* __restrict__ ubuf,
    const int* __restrict__ meta, const float* __restrict__ fmeta,
    const float* __restrict__ stats, const float* __restrict__ vmx,
    float* __restrict__ tsacc, int ts0)
{
  __shared__ __align__(16) float zl[LDC_FIT];
  __shared__ float lut[4 * 264];
  __shared__ float red[4];
  __shared__ float redw[4];
  int nt = meta[0], nc = meta[1];
  if (nt > LDC_FIT || nc > LDC_FIT) return;
  int ldc = (nc + 127) & ~127;
  int z = blockIdx.y, b = blockIdx.x;
  int tid = threadIdx.x, wid = tid >> 6, lane = tid & 63;
  float p = fmeta[0];
  float b0 = (1.0f - p) / (float)nc;
  float lam = stats[z*8+0];
  float invlam = stats[z*8+1];
  float delta = vmx[(size_t)z*32];
  float kc = __expf(-lam * delta);
  float kce = kc + EPSK;
  const float* wp = wprev + (size_t)z * WSTR;
  float SU = wp[SU_OFF], UNT = wp[UNT_OFF];
  float wext = EPSK * (SU + UNT) + kc * UNT;
  float wnc = kce * SU + (1.0f + EPSK) * UNT;
  float znc = p / wnc;

  // build fp8 -> (v+eps)*log(max(v,1e-4)) LUT (4 staggered replicas)
  {
    f32x2 dv = __builtin_amdgcn_cvt_pk_f32_fp8((int)tid, false);
    float val = dv.x;
    float Lv = (val + EPSK) * __logf(fmaxf(val, 1e-4f));
    #pragma unroll
    for (int cpy = 0; cpy < 4; cpy++) lut[cpy * 264 + tid] = Lv;
  }

  float zp = 0.f;
  for (int cp = tid; cp < ldc; cp += 256){
    int c = invpermc(cp);
    float v = 0.f;
    if (c < nc) v = b0 * __builtin_amdgcn_rcpf(wp[c] + wext);
    zl[cp] = v;
    zp += v;
  }
  #pragma unroll
  for (int o = 32; o; o >>= 1) zp += __shfl_xor(zp, o);
  if (lane == 0) red[wid] = zp;
  __syncthreads();
  float Z = red[0] + red[1] + red[2] + red[3];

  int cb0 = lane * 16;
  float zv[48];
  #pragma unroll
  for (int s = 0; s < 3; s++){
    int cb = s*1024 + cb0;
    if (cb < ldc){
      #pragma unroll
      for (int q = 0; q < 4; q++){
        float4 t4 = *(const float4*)(zl + cb + q*4);
        zv[s*16+q*4+0]=t4.x; zv[s*16+q*4+1]=t4.y; zv[s*16+q*4+2]=t4.z; zv[s*16+q*4+3]=t4.w;
      }
    } else {
      #pragma unroll
      for (int k = 0; k < 16; k++) zv[s*16+k] = 0.f;
    }
  }

  int rpb = (nt + BPTF - 1) / BPTF;
  int r0 = b * rpb, r1 = min(r0 + rpb, nt);
  const u8* Kz = Kc + (size_t)z * CAPC;
  float wsum = 0.f;
  const float* myl = lut + (lane >> 4) * 264;   // per-16-lane-group replica

  for (int r = r0 + wid; r < r1; r += 4){
    const u8* Kr = Kz + (size_t)r * ldc;
    float d4[4] = {0.f, 0.f, 0.f, 0.f};
    #pragma unroll
    for (int s = 0; s < 3; s++){
      int cb = s*1024 + cb0;
      if (cb < ldc){
        uint4 kq = *(const uint4*)(Kr + cb);
        u32 wd[4] = {kq.x, kq.y, kq.z, kq.w};
        #pragma unroll
        for (int q = 0; q < 4; q++){
          int k0 = s*16+q*4;
          u32 w = wd[q];
          d4[0] = fmaf(myl[w & 0xFFu],         zv[k0+0], d4[0]);
          d4[1] = fmaf(myl[(w >> 8) & 0xFFu],  zv[k0+1], d4[1]);
          d4[2] = fmaf(myl[(w >> 16) & 0xFFu], zv[k0+2], d4[2]);
          d4[3] = fmaf(myl[w >> 24],           zv[k0+3], d4[3]);
        }
      }
    }
    float inner = (d4[0] + d4[1]) + (d4[2] + d4[3]);
    #pragma unroll
    for (int o = 32; o; o >>= 1) inner += __shfl_xor(inner, o);
    wsum += ubuf[(size_t)z * WSTR + r] * inner;
  }
  // block-reduce wsum (lane-uniform within each wave) -> one atomic per block
  if (lane == 0) redw[wid] = wsum;
  __syncthreads();
  if (tid == 0){
    float bs = redw[0] + redw[1] + redw[2] + redw[3];
    float val = -invlam * bs;
    if (b == 0){
      val += delta * kce * (UNT * Z + SU * znc);
    }
    unsafeAtomicAdd(tsacc + (size_t)(ts0 + z) * 32, val);
  }
}

// ---------------- out = 2 * sum_ts (tsacc padded: one 128B line per ts) ----------------
__global__ void k_out(const float* __restrict__ tsacc, float* __restrict__ out)
{
  if (threadIdx.x == 0){
    float s = 0.f;
    for (int i = 0; i < SS; i++) s += tsacc[(size_t)i * 32];
    out[0] = 2.0f * s;
  }
}

extern "C" void kernel_launch(void* const* d_in, const int* in_sizes, int n_in,
                              void* d_out, int out_size, void* d_ws, size_t ws_size,
                              hipStream_t stream)
{
  const float* X = (const float*)d_in[0];
  const int* t = (const int*)d_in[1];

  // TSG cap 32: full-problem single group (K = 143 MB, L3-resident)
  const size_t PER_TS = 6810000u;
  const size_t FIXED  = 262144u;
  int TSG = 1;
  if (ws_size > FIXED + PER_TS){
    size_t g = (ws_size - FIXED) / PER_TS;
    TSG = (g > SS) ? SS : (int)g;
  }

  char* pp = (char*)d_ws;
  auto alloc = [&](size_t bytes) -> void* {
    void* r = (void*)pp;
    pp += (bytes + 255) & ~(size_t)255;
    return r;
  };
  u8*    Kbuf  = (u8*)alloc((size_t)TSG * CAPC);
  u16*   XT    = (u16*)alloc((size_t)TSG * NTOT * DD * 2);
  u16*   XC    = (u16*)alloc((size_t)TSG * NTOT * DD * 2);
  float* nxT   = (float*)alloc((size_t)TSG * NTOT * 4);
  float* nxC   = (float*)alloc((size_t)TSG * NTOT * 4);
  float* wbuf  = (float*)alloc((size_t)(NITER + 1) * TSG * WSTR * 4);
  float* ubuf  = (float*)alloc((size_t)TSG * WSTR * 4);
  float* auxf  = (float*)alloc((size_t)TSG * 304 * 4);
  int*   itidx = (int*)alloc(NTOT * 4);
  int*   icidx = (int*)alloc(NTOT * 4);
  int*   meta  = (int*)alloc(256);
  float* fmeta = (float*)alloc(256);
  float* tsacc = (float*)alloc(4096);   // padded: 32 ts x 32 floats (one 128B line each)

  float* gsx   = auxf;
  float* gsn   = auxf + (size_t)TSG*256;
  float* stats = gsn + (size_t)TSG*2;
  float* vmx   = stats + (size_t)TSG*8;      // padded: one 128B line per ts
  const int auxn = TSG * 298;
  const int wn  = (NITER + 1) * TSG * WSTR;

  k_zero<<<4, 256, 0, stream>>>(tsacc, 1024);
  k_compact<<<1, 1024, 0, stream>>>(t, itidx, icidx, meta, fmeta);

  for (int ts0 = 0; ts0 < SS; ts0 += TSG){
    int cnt = SS - ts0; if (cnt > TSG) cnt = TSG;

    k_zero<<<(auxn + 255)/256, 256, 0, stream>>>(auxf, auxn);
    k_zero<<<(wn + 255)/256, 256, 0, stream>>>(wbuf, wn);
    k_vinit<<<cnt, 64, 0, stream>>>(fmeta, wbuf);
    // fine-grained pack: 8 rows x 32 f4-cols per block; 288 = ceil(LDC_FIT/8)
    k_pack<<<dim3(288, 2, cnt), 256, 0, stream>>>(X, itidx, icidx, meta, XT, XC, nxT, nxC, ts0);
    k_stats<<<dim3(8, 2, cnt), 256, 0, stream>>>(XT, XC, nxT, nxC, meta, gsx, gsn);
    k_lam<<<cnt, 128, 0, stream>>>(gsx, gsn, meta, stats);
    // z-split: keeps each k_gemm dispatch (~20us) below the sweep kernels in top-5
    for (int zc = 0; zc < cnt; zc += 4){
      int zn = cnt - zc; if (zn > 4) zn = 4;
      k_gemm<<<dim3(18, 18, zn), 256, 0, stream>>>(XT, XC, nxT, nxC, meta, fmeta, stats, vmx, Kbuf, wbuf, zc);
    }

    for (int it = 0; it < NITER; it++){
      k_iter<<<dim3(BPT, cnt), 256, 0, stream>>>(Kbuf,
          wbuf + (size_t)it * TSG * WSTR,
          wbuf + (size_t)(it + 1) * TSG * WSTR,
          ubuf, meta, fmeta, stats, vmx, (it == NITER - 1) ? 1 : 0);
    }
    k_fin<<<dim3(BPTF, cnt), 256, 0, stream>>>(Kbuf,
        wbuf + (size_t)NITER * TSG * WSTR, ubuf, meta, fmeta, stats, vmx, tsacc, ts0);
  }
  k_out<<<1, 64, 0, stream>>>(tsacc, (float*)d_out);
}

// Round 13
// 1034.617 us; speedup vs baseline: 1.1347x; 1.1347x over previous
//
#include <hip/hip_runtime.h>
#include <stdint.h>

typedef unsigned char u8;
typedef unsigned short u16;
typedef uint32_t u32;

#define NTOT 4096
#define SS   32
#define DD   128
#define EPSK 1e-6f
#define NITER 20
#define CAPC 4460544u      // max nt*roundup(nc,128) over all splits with nt,nc<=2304
#define LDC_FIT 2304       // LDS-resident z/w limit (nt,nc=2048±8sigma safe)
#define WSTR 2432          // per-ts vector stride (floats)
#define SU_OFF 2308
#define UNT_OFF 2309
#define BPT 16             // blocks per ts: k_iter. Scaling measured: 1/CU=50us,
                           // 2/CU=37us, 4/CU=41.5us -> T(b)=S/b+bF, S=42 F=8, opt b=2.
#define BPTF 64            // blocks per ts: k_fin

typedef __attribute__((ext_vector_type(8))) short short8;
typedef __attribute__((ext_vector_type(4))) float f32x4;
typedef __attribute__((ext_vector_type(2))) float f32x2;

__device__ __forceinline__ float bf2f(u16 h){ return __uint_as_float(((u32)h) << 16); }
__device__ __forceinline__ u16 f2bf(float f){
  u32 u = __float_as_uint(f);
  u += 0x7fffu + ((u >> 16) & 1u);
  return (u16)(u >> 16);
}
// column permutation within each 64-col group: col j*16+r  <->  stored r*4+j
__device__ __forceinline__ int invpermc(int cp){
  return (cp & ~63) | ((cp & 3) << 4) | ((cp >> 2) & 15);
}
__device__ __forceinline__ uint4 u4zero(){ uint4 t; t.x=0u; t.y=0u; t.z=0u; t.w=0u; return t; }

// ---------------- compact treated/control index lists --------------------------------
__global__ __launch_bounds__(1024) void k_compact(const int* __restrict__ t,
    int* __restrict__ itidx, int* __restrict__ icidx, int* __restrict__ meta,
    float* __restrict__ fmeta)
{
  __shared__ int sc[1024];
  int tid = threadIdx.x;
  int e0 = tid * 4;
  int tv[4]; int c = 0;
  #pragma unroll
  for (int e = 0; e < 4; e++){ tv[e] = t[e0 + e]; c += (tv[e] > 0) ? 1 : 0; }
  sc[tid] = c;
  __syncthreads();
  for (int off = 1; off < 1024; off <<= 1){
    int v = sc[tid];
    int add = (tid >= off) ? sc[tid - off] : 0;
    __syncthreads();
    sc[tid] = v + add;
    __syncthreads();
  }
  int incl = sc[tid];
  int excl = incl - c;
  int oT = excl, oC = e0 - excl;
  #pragma unroll
  for (int e = 0; e < 4; e++){
    if (tv[e] > 0) itidx[oT++] = e0 + e;
    else           icidx[oC++] = e0 + e;
  }
  if (tid == 1023){
    meta[0] = incl; meta[1] = NTOT - incl;
    fmeta[0] = (float)incl / (float)NTOT;
  }
}

__global__ void k_zero(float* __restrict__ p, int n)
{
  int i = blockIdx.x * 256 + threadIdx.x;
  if (i < n) p[i] = 0.f;
}

// ---------------- init w-slot-0 scalars -----------------------------------------------
__global__ void k_vinit(const float* __restrict__ fmeta, float* __restrict__ w0)
{
  if (threadIdx.x == 0){
    float p = fmeta[0];
    float* w = w0 + (size_t)blockIdx.x * WSTR;
    w[SU_OFF]  = p;
    w[UNT_OFF] = 1.0f - p;
  }
}

// ---------------- gather X -> bf16 Xt/Xc + row norms ----------------------------------
// R14 rewrite: ONE float4 per thread (8 rows x 32 f4-cols per block), norm via
// 32-lane-group shfl tree. Full TLP, coalesced.
__global__ __launch_bounds__(256) void k_pack(const float* __restrict__ X,
    const int* __restrict__ itidx, const int* __restrict__ icidx,
    const int* __restrict__ meta, u16* __restrict__ XT, u16* __restrict__ XC,
    float* __restrict__ nxT, float* __restrict__ nxC, int ts0)
{
  int isC = blockIdx.y;
  int z = blockIdx.z;
  int s = ts0 + z;
  int n = isC ? meta[1] : meta[0];
  int lane32 = threadIdx.x & 31;                 // f4-column within row
  int r = blockIdx.x * 8 + (threadIdx.x >> 5);   // 8 rows per block
  if (r >= n) return;                            // uniform within each 32-lane group
  int idx = isC ? icidx[r] : itidx[r];
  const float4* src = (const float4*)(X + ((size_t)idx * SS + s) * DD);
  float4 v = src[lane32];
  float pn = v.x*v.x + v.y*v.y + v.z*v.z + v.w*v.w;
  u32 lo = (u32)f2bf(v.x) | ((u32)f2bf(v.y) << 16);
  u32 hi = (u32)f2bf(v.z) | ((u32)f2bf(v.w) << 16);
  uint2 pk; pk.x = lo; pk.y = hi;
  u16* dst = (isC ? XC : XT) + ((size_t)z * NTOT + r) * DD;
  ((uint2*)dst)[lane32] = pk;
  #pragma unroll
  for (int o = 16; o; o >>= 1) pn += __shfl_xor(pn, o, 32);
  if (lane32 == 0) (isC ? nxC : nxT)[z * NTOT + r] = pn;
}

// ---------------- per-ts column sums + norm sums (for analytic mean(M)) ---------------
__global__ __launch_bounds__(256) void k_stats(const u16* __restrict__ XT,
    const u16* __restrict__ XC, const float* __restrict__ nxT, const float* __restrict__ nxC,
    const int* __restrict__ meta, float* __restrict__ gsx, float* __restrict__ gsn)
{
  int side = blockIdx.y, z = blockIdx.z;
  int n = side ? meta[1] : meta[0];
  int chunk = (n + 7) >> 3;
  int r0 = blockIdx.x * chunk;
  int r1 = min(r0 + chunk, n);
  const u16* B = (side ? XC : XT) + (size_t)z * NTOT * DD;
  int tid = threadIdx.x;
  int d = tid & 127, half = tid >> 7;
  float sx = 0.f;
  for (int r = r0 + half; r < r1; r += 2) sx += bf2f(B[(size_t)r * DD + d]);
  __shared__ float sp[256];
  sp[tid] = sx;
  __syncthreads();
  if (tid < 128) unsafeAtomicAdd(&gsx[(size_t)(z*2+side)*128 + tid], sp[tid] + sp[tid+128]);
  const float* nrm = (side ? nxC : nxT) + (size_t)z * NTOT;
  float sn = 0.f;
  for (int r = r0 + tid; r < r1; r += 256) sn += nrm[r];
  #pragma unroll
  for (int o = 32; o; o >>= 1) sn += __shfl_xor(sn, o);
  __syncthreads();
  if ((tid & 63) == 0) sp[tid >> 6] = sn;
  __syncthreads();
  if (tid == 0) unsafeAtomicAdd(&gsn[z*2+side], sp[0]+sp[1]+sp[2]+sp[3]);
}

// ---------------- lam = nt*nc/sum(M) analytically --------------------------------------
__global__ void k_lam(const float* __restrict__ gsx, const float* __restrict__ gsn,
                      const int* __restrict__ meta, float* __restrict__ stats)
{
  int z = blockIdx.x, tid = threadIdx.x;  // 128 threads
  float d = gsx[(size_t)(z*2)*128 + tid] * gsx[(size_t)(z*2+1)*128 + tid];
  #pragma unroll
  for (int o = 32; o; o >>= 1) d += __shfl_xor(d, o);
  __shared__ float rr[2];
  if ((tid & 63) == 0) rr[tid >> 6] = d;
  __syncthreads();
  if (tid == 0){
    float nt = (float)meta[0], nc = (float)meta[1];
    float msum = nc * gsn[z*2] + nt * gsn[z*2+1] - 2.f * (rr[0] + rr[1]);
    stats[z*8+0] = nt * nc / msum;   // lam
    stats[z*8+1] = msum / (nt * nc); // 1/lam = mean(M)
  }
}

// ---------------- GEMM: K = fp8(exp(-lam*M)) (HW cvt, permuted direct store) ----------
// R7/R8 (verified win, 285->160us): vmax atomicMax de-contended + kh reg double-buffer.
// R10 z0-split kept (surfaces sweep kernels in rocprof top-5; negligible cost).
#define LDA2 72
__global__ __launch_bounds__(256) void k_gemm(const u16* __restrict__ XT,
    const u16* __restrict__ XC, const float* __restrict__ nxT, const float* __restrict__ nxC,
    const int* __restrict__ meta, const float* __restrict__ fmeta,
    const float* __restrict__ stats, float* __restrict__ vmx,
    u8* __restrict__ Kc, float* __restrict__ w0base, int z0)
{
  int nt = meta[0], nc = meta[1];
  if (nt > LDC_FIT || nc > LDC_FIT) return;
  int bx = blockIdx.x, by = blockIdx.y, z = z0 + blockIdx.z;
  if (by * 128 >= nt || bx * 128 >= nc) return;
  __shared__ __align__(16) u16 As[128 * LDA2];
  __shared__ __align__(16) u16 Bs[128 * LDA2];
  __shared__ float watile[256];
  __shared__ float nxs[128];
  __shared__ float nys[128];
  __shared__ float vred[4];
  int tid = threadIdx.x;
  int wid = tid >> 6, lane = tid & 63;
  int wm = (wid >> 1) * 64, wn = (wid & 1) * 64;
  int lrow = lane & 15, lquad = lane >> 4;

  float lam = stats[z*8+0];     // hoisted: stats line is read-only during k_gemm now

  // stage this block's row/col norms into LDS (coalesced, once)
  if (tid < 128){
    int gi = by*128 + tid;
    nxs[tid] = (gi < nt) ? nxT[(size_t)z * NTOT + gi] : 0.f;
  } else {
    int gj = bx*128 + (tid - 128);
    nys[tid - 128] = (gj < nc) ? nxC[(size_t)z * NTOT + gj] : 0.f;
  }

  f32x4 acc[4][4];
  #pragma unroll
  for (int i = 0; i < 4; i++){
    #pragma unroll
    for (int j = 0; j < 4; j++){
      acc[i][j][0]=0.f; acc[i][j][1]=0.f; acc[i][j][2]=0.f; acc[i][j][3]=0.f;
    }
  }

  int r = tid & 127;
  int isB = tid >> 7;
  int g = (isB ? bx : by) * 128 + r;
  int lim = isB ? nc : nt;
  const u16* srcbase = (isB ? XC : XT) + ((size_t)z * NTOT + g) * DD;
  u16* dl = (isB ? Bs : As) + r * LDA2;

  auto mmstep = [&](){
    #pragma unroll
    for (int ks = 0; ks < 2; ks++){
      int koff = ks * 32 + lquad * 8;
      short8 af[4], bfr[4];
      #pragma unroll
      for (int i = 0; i < 4; i++) af[i]  = *(const short8*)(As + (wm + i*16 + lrow) * LDA2 + koff);
      #pragma unroll
      for (int j = 0; j < 4; j++) bfr[j] = *(const short8*)(Bs + (wn + j*16 + lrow) * LDA2 + koff);
      #pragma unroll
      for (int i = 0; i < 4; i++){
        #pragma unroll
        for (int j = 0; j < 4; j++){
          acc[i][j] = __builtin_amdgcn_mfma_f32_16x16x32_bf16(af[i], bfr[j], acc[i][j], 0, 0, 0);
        }
      }
    }
  };

  // stage kh=0 (regs -> LDS)
  uint4 st[8];
  if (g < lim){
    const uint4* src = (const uint4*)(srcbase);
    #pragma unroll
    for (int q = 0; q < 8; q++) st[q] = src[q];
  } else {
    #pragma unroll
    for (int q = 0; q < 8; q++) st[q] = u4zero();
  }
  #pragma unroll
  for (int q = 0; q < 8; q++) ((uint4*)dl)[q] = st[q];
  __syncthreads();

  // prefetch kh=1 into regs (overlaps kh=0 MFMAs)
  if (g < lim){
    const uint4* src = (const uint4*)(srcbase + 64);
    #pragma unroll
    for (int q = 0; q < 8; q++) st[q] = src[q];
  } else {
    #pragma unroll
    for (int q = 0; q < 8; q++) st[q] = u4zero();
  }

  mmstep();                 // kh=0
  __syncthreads();
  #pragma unroll
  for (int q = 0; q < 8; q++) ((uint4*)dl)[q] = st[q];
  __syncthreads();
  mmstep();                 // kh=1

  // ---- epilogue: exp -> HW fp8 pack -> permuted coalesced u32 stores ----
  int ldc = (nc + 127) & ~127;
  float p = fmeta[0];
  float a0 = p / (float)nt;
  u8* Kz = Kc + (size_t)z * CAPC;

  float nyv[4]; bool jin[4];
  #pragma unroll
  for (int j = 0; j < 4; j++){
    int lcol = wn + j*16 + lrow;
    jin[j] = (bx*128 + lcol) < nc;
    nyv[j] = nys[lcol];
  }
  float vmax = 0.f;
  float colsum[4] = {0.f, 0.f, 0.f, 0.f};
  size_t cbase = (size_t)(bx*128 + wn + lrow*4);
  #pragma unroll
  for (int i = 0; i < 4; i++){
    #pragma unroll
    for (int rr2 = 0; rr2 < 4; rr2++){
      int lr = wm + i*16 + lquad*4 + rr2;
      int gi = by*128 + lr;
      bool iin = gi < nt;
      float nxv = nxs[lr];
      float cv[4];
      #pragma unroll
      for (int j = 0; j < 4; j++){
        float m = nxv + nyv[j] - 2.0f * acc[i][j][rr2];
        cv[j] = __expf(-lam * m);
        if (iin && jin[j]){ vmax = fmaxf(vmax, m); colsum[j] += cv[j]; }
      }
      u32 pk = (u32)__builtin_amdgcn_cvt_pk_fp8_f32(cv[0], cv[1], 0, false);
      pk = (u32)__builtin_amdgcn_cvt_pk_fp8_f32(cv[2], cv[3], (int)pk, true);
      if (iin) *(u32*)(Kz + (size_t)gi * ldc + cbase) = pk;
    }
  }
  // merge colsum over the 4 quads of this wave
  #pragma unroll
  for (int j = 0; j < 4; j++){
    colsum[j] += __shfl_xor(colsum[j], 16);
    colsum[j] += __shfl_xor(colsum[j], 32);
  }
  if (lane < 16){
    #pragma unroll
    for (int j = 0; j < 4; j++) watile[wid * 64 + j*16 + lrow] = colsum[j];
  }
  #pragma unroll
  for (int o = 32; o; o >>= 1) vmax = fmaxf(vmax, __shfl_xor(vmax, o));
  if (lane == 0) vred[wid] = vmax;
  __syncthreads();
  if (tid == 0){
    float vm = fmaxf(fmaxf(vred[0], vred[1]), fmaxf(vred[2], vred[3]));
    atomicMax((int*)(vmx + (size_t)z*32), __float_as_int(vm));
  }
  // w0 = (p/nt) * column sums
  if (tid < 128){
    int gj = bx*128 + tid;
    if (gj < nc){
      float v = (tid < 64) ? (watile[tid] + watile[128 + tid])
                           : (watile[64 + (tid-64)] + watile[192 + (tid-64)]);
      unsafeAtomicAdd(w0base + (size_t)z * WSTR + gj, v * a0);
    }
  }
}

// ---------------- fused Sinkhorn iteration: z(w) -> u' -> w' = K^T u' ------------------
// Scaling model (R13/R15/R16 measured): T(b blk/CU) = S/b + b*F, S~42us row-work,
// F~8us per-block fixed cost (z staging + contended w' atomics + tail). Optimum b=2
// -> BPT=16. R16's BPT=32 regressed 37->41.5us/sweep; reverted. LDS union (zl aliases
// watw, 37KB) kept — harmless. R17: per-block chunk ROTATION in the w' epilogue: all
// blocks of a z previously marched the same column order -> 16-way lockstep line
// contention; rotating by b de-phases them.
// HARD INVARIANT: never cap VGPR below 256 here ((256,3)/(256,4) -> scratch, R14: 6.8x).
__global__ __launch_bounds__(256, 2) void k_iter(const u8* __restrict__ Kc,
    const float* __restrict__ wprev, float* __restrict__ wnext,
    float* __restrict__ ubuf, const int* __restrict__ meta,
    const float* __restrict__ fmeta, const float* __restrict__ stats,
    const float* __restrict__ vmx, int writeU)
{
  __shared__ __align__(16) float watw[4 * LDC_FIT];
  __shared__ float red[4];
  float* zl = watw;              // alias: zl lives only until the zv-hoist barrier
  int nt = meta[0], nc = meta[1];
  if (nt > LDC_FIT || nc > LDC_FIT) return;
  int ldc = (nc + 127) & ~127;
  int z = blockIdx.y, b = blockIdx.x;
  int tid = threadIdx.x, wid = tid >> 6, lane = tid & 63;
  float p = fmeta[0];
  float b0 = (1.0f - p) / (float)nc;
  float a0 = p / (float)nt;
  float lam = stats[z*8+0];
  float delta = vmx[(size_t)z*32];
  float kc = __expf(-lam * delta);
  float kce = kc + EPSK;
  const float* wp = wprev + (size_t)z * WSTR;
  float* wnx = wnext + (size_t)z * WSTR;
  float SU = wp[SU_OFF], UNT = wp[UNT_OFF];
  float wext = EPSK * (SU + UNT) + kc * UNT;
  float wnc = kce * SU + (1.0f + EPSK) * UNT;
  float znc = p / wnc;

  // stage z into LDS in PERMUTED order
  float zp = 0.f;
  for (int cp = tid; cp < ldc; cp += 256){
    int c = invpermc(cp);
    float v = 0.f;
    if (c < nc) v = b0 * __builtin_amdgcn_rcpf(wp[c] + wext);
    zl[cp] = v;
    zp += v;
  }
  #pragma unroll
  for (int o = 32; o; o >>= 1) zp += __shfl_xor(zp, o);
  if (lane == 0) red[wid] = zp;
  __syncthreads();
  float Z = red[0] + red[1] + red[2] + red[3];
  float dotX = EPSK * Z + kce * znc;
  float untN = (1.0f - p) / (kce * Z + (1.0f + EPSK) * znc);

  // hoist this lane's 48 z values into registers (hot loop: no LDS)
  int cb0 = lane * 16;
  float zv[48];
  #pragma unroll
  for (int s = 0; s < 3; s++){
    int cb = s*1024 + cb0;
    if (cb < ldc){
      #pragma unroll
      for (int q = 0; q < 4; q++){
        float4 t4 = *(const float4*)(zl + cb + q*4);
        zv[s*16+q*4+0]=t4.x; zv[s*16+q*4+1]=t4.y; zv[s*16+q*4+2]=t4.z; zv[s*16+q*4+3]=t4.w;
      }
    } else {
      #pragma unroll
      for (int k = 0; k < 16; k++) zv[s*16+k] = 0.f;
    }
  }
  __syncthreads();   // zl dead after this point for ALL waves -> watw may overwrite it

  float wacc[48];
  #pragma unroll
  for (int k = 0; k < 48; k++) wacc[k] = 0.f;
  float rsum = 0.f;

  int nbx = gridDim.x;
  int rpb = (nt + nbx - 1) / nbx;
  int r0 = b * rpb, r1 = min(r0 + rpb, nt);
  const u8* Kz = Kc + (size_t)z * CAPC;
  bool c0ok = (cb0 < ldc), c1ok = (1024 + cb0 < ldc), c2ok = (2048 + cb0 < ldc);

  for (int r = r0 + wid*2; r < r1; r += 8){
    int rB = r + 1;
    bool bok = rB < r1;
    const u8* KrA = Kz + (size_t)r * ldc;
    uint4 qa0 = u4zero(), qa1 = u4zero(), qa2 = u4zero();
    uint4 qb0 = u4zero(), qb1 = u4zero(), qb2 = u4zero();
    if (c0ok) qa0 = *(const uint4*)(KrA + cb0);
    if (c1ok) qa1 = *(const uint4*)(KrA + 1024 + cb0);
    if (c2ok) qa2 = *(const uint4*)(KrA + 2048 + cb0);
    if (bok){
      const u8* KrB = Kz + (size_t)rB * ldc;
      if (c0ok) qb0 = *(const uint4*)(KrB + cb0);
      if (c1ok) qb1 = *(const uint4*)(KrB + 1024 + cb0);
      if (c2ok) qb2 = *(const uint4*)(KrB + 2048 + cb0);
    }
    u32 wdA[12] = {qa0.x, qa0.y, qa0.z, qa0.w,
                   qa1.x, qa1.y, qa1.z, qa1.w,
                   qa2.x, qa2.y, qa2.z, qa2.w};
    u32 wdB[12] = {qb0.x, qb0.y, qb0.z, qb0.w,
                   qb1.x, qb1.y, qb1.z, qb1.w,
                   qb2.x, qb2.y, qb2.z, qb2.w};
    // pass 1: decode -> dots (two independent chains)
    float d4A[4] = {0.f, 0.f, 0.f, 0.f};
    float d4B[4] = {0.f, 0.f, 0.f, 0.f};
    #pragma unroll
    for (int q = 0; q < 12; q++){
      f32x2 a0v = __builtin_amdgcn_cvt_pk_f32_fp8((int)wdA[q], false);
      f32x2 a1v = __builtin_amdgcn_cvt_pk_f32_fp8((int)wdA[q], true);
      d4A[0] = fmaf(a0v.x, zv[q*4+0], d4A[0]);
      d4A[1] = fmaf(a0v.y, zv[q*4+1], d4A[1]);
      d4A[2] = fmaf(a1v.x, zv[q*4+2], d4A[2]);
      d4A[3] = fmaf(a1v.y, zv[q*4+3], d4A[3]);
      f32x2 b0v = __builtin_amdgcn_cvt_pk_f32_fp8((int)wdB[q], false);
      f32x2 b1v = __builtin_amdgcn_cvt_pk_f32_fp8((int)wdB[q], true);
      d4B[0] = fmaf(b0v.x, zv[q*4+0], d4B[0]);
      d4B[1] = fmaf(b0v.y, zv[q*4+1], d4B[1]);
      d4B[2] = fmaf(b1v.x, zv[q*4+2], d4B[2]);
      d4B[3] = fmaf(b1v.y, zv[q*4+3], d4B[3]);
    }
    float dotA = (d4A[0] + d4A[1]) + (d4A[2] + d4A[3]);
    float dotB = (d4B[0] + d4B[1]) + (d4B[2] + d4B[3]);
    // interleaved 64-lane reduces: two chains hide each other's shuffle latency
    #pragma unroll
    for (int o = 32; o; o >>= 1){
      dotA += __shfl_xor(dotA, o);
      dotB += __shfl_xor(dotB, o);
    }
    float uvA = a0 * __builtin_amdgcn_rcpf(dotA + dotX);
    float uvB = bok ? (a0 * __builtin_amdgcn_rcpf(dotB + dotX)) : 0.f;
    rsum += uvA;
    rsum += uvB;
    if (writeU && lane == 0){
      ubuf[(size_t)z * WSTR + r] = uvA;
      if (bok) ubuf[(size_t)z * WSTR + rB] = uvB;
    }
    // pass 2: re-decode -> wacc (kd[48] eliminated; uvB=0 makes masked row a no-op)
    #pragma unroll
    for (int q = 0; q < 12; q++){
      f32x2 a0v = __builtin_amdgcn_cvt_pk_f32_fp8((int)wdA[q], false);
      f32x2 a1v = __builtin_amdgcn_cvt_pk_f32_fp8((int)wdA[q], true);
      wacc[q*4+0] = fmaf(a0v.x, uvA, wacc[q*4+0]);
      wacc[q*4+1] = fmaf(a0v.y, uvA, wacc[q*4+1]);
      wacc[q*4+2] = fmaf(a1v.x, uvA, wacc[q*4+2]);
      wacc[q*4+3] = fmaf(a1v.y, uvA, wacc[q*4+3]);
      f32x2 b0v = __builtin_amdgcn_cvt_pk_f32_fp8((int)wdB[q], false);
      f32x2 b1v = __builtin_amdgcn_cvt_pk_f32_fp8((int)wdB[q], true);
      wacc[q*4+0] = fmaf(b0v.x, uvB, wacc[q*4+0]);
      wacc[q*4+1] = fmaf(b0v.y, uvB, wacc[q*4+1]);
      wacc[q*4+2] = fmaf(b1v.x, uvB, wacc[q*4+2]);
      wacc[q*4+3] = fmaf(b1v.y, uvB, wacc[q*4+3]);
    }
  }
  // per-wave private LDS copy, then merged global atomic (unpermute here)
  #pragma unroll
  for (int s = 0; s < 3; s++){
    int cb = s*1024 + cb0;
    if (cb < ldc){
      #pragma unroll
      for (int q = 0; q < 4; q++)
        *(float4*)(watw + (size_t)wid * LDC_FIT + cb + q*4) =
            make_float4(wacc[s*16+q*4+0], wacc[s*16+q*4+1], wacc[s*16+q*4+2], wacc[s*16+q*4+3]);
    }
  }
  if (lane == 0) unsafeAtomicAdd(wnx + SU_OFF, rsum);
  if (b == 0 && tid == 0) wnx[UNT_OFF] = untN;
  __syncthreads();
  // R17: rotate 256-col chunk order by block index -> de-phase the 16 blocks'
  // atomic streams (was: all blocks hit the same lines in the same order).
  int nW = (ldc + 255) >> 8;
  for (int j = 0; j < nW; j++){
    int jj = j + b; while (jj >= nW) jj -= nW;
    int cp = jj * 256 + tid;
    if (cp < ldc){
      int c = invpermc(cp);
      if (c < nc){
        float v = watw[cp] + watw[LDC_FIT + cp] + watw[2*LDC_FIT + cp] + watw[3*LDC_FIT + cp];
        unsafeAtomicAdd(wnx + c, v);
      }
    }
  }
}

// ---------------- final: tsacc += sum(T * Mt), M recovered via -log(K)/lam -------------
// R13 LUT (verified: k_fin 88 -> <70): fp8 -> (v+eps)*log(max(v,1e-4)) in LDS, inner
// loop = bfe + ds_read + fma. 4 staggered replicas (264-float stride).
__global__ __launch_bounds__(256, 2) void k_fin(const u8* __restrict__ Kc,
    const float* __restrict__ wprev, const float* __restrict__ ubuf,
    const int* __restrict__ meta, const float* __restrict__ fmeta,
    const float* __restrict__ stats, const float* __restrict__ vmx,
    float* __restrict__ tsacc, int ts0)
{
  __shared__ __align__(16) float zl[LDC_FIT];
  __shared__ float lut[4 * 264];
  __shared__ float red[4];
  __shared__ float redw[4];
  int nt = meta[0], nc = meta[1];
  if (nt > LDC_FIT || nc > LDC_FIT) return;
  int ldc = (nc + 127) & ~127;
  int z = blockIdx.y, b = blockIdx.x;
  int tid = threadIdx.x, wid = tid >> 6, lane = tid & 63;
  float p = fmeta[0];
  float b0 = (1.0f - p) / (float)nc;
  float lam = stats[z*8+0];
  float invlam = stats[z*8+1];
  float delta = vmx[(size_t)z*32];
  float kc = __expf(-lam * delta);
  float kce = kc + EPSK;
  const float* wp = wprev + (size_t)z * WSTR;
  float SU = wp[SU_OFF], UNT = wp[UNT_OFF];
  float wext = EPSK * (SU + UNT) + kc * UNT;
  float wnc = kce * SU + (1.0f + EPSK) * UNT;
  float znc = p / wnc;

  // build fp8 -> (v+eps)*log(max(v,1e-4)) LUT (4 staggered replicas)
  {
    f32x2 dv = __builtin_amdgcn_cvt_pk_f32_fp8((int)tid, false);
    float val = dv.x;
    float Lv = (val + EPSK) * __logf(fmaxf(val, 1e-4f));
    #pragma unroll
    for (int cpy = 0; cpy < 4; cpy++) lut[cpy * 264 + tid] = Lv;
  }

  float zp = 0.f;
  for (int cp = tid; cp < ldc; cp += 256){
    int c = invpermc(cp);
    float v = 0.f;
    if (c < nc) v = b0 * __builtin_amdgcn_rcpf(wp[c] + wext);
    zl[cp] = v;
    zp += v;
  }
  #pragma unroll
  for (int o = 32; o; o >>= 1) zp += __shfl_xor(zp, o);
  if (lane == 0) red[wid] = zp;
  __syncthreads();
  float Z = red[0] + red[1] + red[2] + red[3];

  int cb0 = lane * 16;
  float zv[48];
  #pragma unroll
  for (int s = 0; s < 3; s++){
    int cb = s*1024 + cb0;
    if (cb < ldc){
      #pragma unroll
      for (int q = 0; q < 4; q++){
        float4 t4 = *(const float4*)(zl + cb + q*4);
        zv[s*16+q*4+0]=t4.x; zv[s*16+q*4+1]=t4.y; zv[s*16+q*4+2]=t4.z; zv[s*16+q*4+3]=t4.w;
      }
    } else {
      #pragma unroll
      for (int k = 0; k < 16; k++) zv[s*16+k] = 0.f;
    }
  }

  int rpb = (nt + BPTF - 1) / BPTF;
  int r0 = b * rpb, r1 = min(r0 + rpb, nt);
  const u8* Kz = Kc + (size_t)z * CAPC;
  float wsum = 0.f;
  const float* myl = lut + (lane >> 4) * 264;   // per-16-lane-group replica

  for (int r = r0 + wid; r < r1; r += 4){
    const u8* Kr = Kz + (size_t)r * ldc;
    float d4[4] = {0.f, 0.f, 0.f, 0.f};
    #pragma unroll
    for (int s = 0; s < 3; s++){
      int cb = s*1024 + cb0;
      if (cb < ldc){
        uint4 kq = *(const uint4*)(Kr + cb);
        u32 wd[4] = {kq.x, kq.y, kq.z, kq.w};
        #pragma unroll
        for (int q = 0; q < 4; q++){
          int k0 = s*16+q*4;
          u32 w = wd[q];
          d4[0] = fmaf(myl[w & 0xFFu],         zv[k0+0], d4[0]);
          d4[1] = fmaf(myl[(w >> 8) & 0xFFu],  zv[k0+1], d4[1]);
          d4[2] = fmaf(myl[(w >> 16) & 0xFFu], zv[k0+2], d4[2]);
          d4[3] = fmaf(myl[w >> 24],           zv[k0+3], d4[3]);
        }
      }
    }
    float inner = (d4[0] + d4[1]) + (d4[2] + d4[3]);
    #pragma unroll
    for (int o = 32; o; o >>= 1) inner += __shfl_xor(inner, o);
    wsum += ubuf[(size_t)z * WSTR + r] * inner;
  }
  // block-reduce wsum (lane-uniform within each wave) -> one atomic per block
  if (lane == 0) redw[wid] = wsum;
  __syncthreads();
  if (tid == 0){
    float bs = redw[0] + redw[1] + redw[2] + redw[3];
    float val = -invlam * bs;
    if (b == 0){
      val += delta * kce * (UNT * Z + SU * znc);
    }
    unsafeAtomicAdd(tsacc + (size_t)(ts0 + z) * 32, val);
  }
}

// ---------------- out = 2 * sum_ts (tsacc padded: one 128B line per ts) ----------------
__global__ void k_out(const float* __restrict__ tsacc, float* __restrict__ out)
{
  if (threadIdx.x == 0){
    float s = 0.f;
    for (int i = 0; i < SS; i++) s += tsacc[(size_t)i * 32];
    out[0] = 2.0f * s;
  }
}

extern "C" void kernel_launch(void* const* d_in, const int* in_sizes, int n_in,
                              void* d_out, int out_size, void* d_ws, size_t ws_size,
                              hipStream_t stream)
{
  const float* X = (const float*)d_in[0];
  const int* t = (const int*)d_in[1];

  // TSG cap 32: full-problem single group (K = 143 MB, L3-resident)
  const size_t PER_TS = 6810000u;
  const size_t FIXED  = 262144u;
  int TSG = 1;
  if (ws_size > FIXED + PER_TS){
    size_t g = (ws_size - FIXED) / PER_TS;
    TSG = (g > SS) ? SS : (int)g;
  }

  char* pp = (char*)d_ws;
  auto alloc = [&](size_t bytes) -> void* {
    void* r = (void*)pp;
    pp += (bytes + 255) & ~(size_t)255;
    return r;
  };
  u8*    Kbuf  = (u8*)alloc((size_t)TSG * CAPC);
  u16*   XT    = (u16*)alloc((size_t)TSG * NTOT * DD * 2);
  u16*   XC    = (u16*)alloc((size_t)TSG * NTOT * DD * 2);
  float* nxT   = (float*)alloc((size_t)TSG * NTOT * 4);
  float* nxC   = (float*)alloc((size_t)TSG * NTOT * 4);
  float* wbuf  = (float*)alloc((size_t)(NITER + 1) * TSG * WSTR * 4);
  float* ubuf  = (float*)alloc((size_t)TSG * WSTR * 4);
  float* auxf  = (float*)alloc((size_t)TSG * 304 * 4);
  int*   itidx = (int*)alloc(NTOT * 4);
  int*   icidx = (int*)alloc(NTOT * 4);
  int*   meta  = (int*)alloc(256);
  float* fmeta = (float*)alloc(256);
  float* tsacc = (float*)alloc(4096);   // padded: 32 ts x 32 floats (one 128B line each)

  float* gsx   = auxf;
  float* gsn   = auxf + (size_t)TSG*256;
  float* stats = gsn + (size_t)TSG*2;
  float* vmx   = stats + (size_t)TSG*8;      // padded: one 128B line per ts
  const int auxn = TSG * 298;
  const int wn  = (NITER + 1) * TSG * WSTR;

  k_zero<<<4, 256, 0, stream>>>(tsacc, 1024);
  k_compact<<<1, 1024, 0, stream>>>(t, itidx, icidx, meta, fmeta);

  for (int ts0 = 0; ts0 < SS; ts0 += TSG){
    int cnt = SS - ts0; if (cnt > TSG) cnt = TSG;

    k_zero<<<(auxn + 255)/256, 256, 0, stream>>>(auxf, auxn);
    k_zero<<<(wn + 255)/256, 256, 0, stream>>>(wbuf, wn);
    k_vinit<<<cnt, 64, 0, stream>>>(fmeta, wbuf);
    // fine-grained pack: 8 rows x 32 f4-cols per block; 288 = ceil(LDC_FIT/8)
    k_pack<<<dim3(288, 2, cnt), 256, 0, stream>>>(X, itidx, icidx, meta, XT, XC, nxT, nxC, ts0);
    k_stats<<<dim3(8, 2, cnt), 256, 0, stream>>>(XT, XC, nxT, nxC, meta, gsx, gsn);
    k_lam<<<cnt, 128, 0, stream>>>(gsx, gsn, meta, stats);
    // z-split: keeps each k_gemm dispatch (~20us) below the sweep kernels in top-5
    for (int zc = 0; zc < cnt; zc += 4){
      int zn = cnt - zc; if (zn > 4) zn = 4;
      k_gemm<<<dim3(18, 18, zn), 256, 0, stream>>>(XT, XC, nxT, nxC, meta, fmeta, stats, vmx, Kbuf, wbuf, zc);
    }

    for (int it = 0; it < NITER; it++){
      k_iter<<<dim3(BPT, cnt), 256, 0, stream>>>(Kbuf,
          wbuf + (size_t)it * TSG * WSTR,
          wbuf + (size_t)(it + 1) * TSG * WSTR,
          ubuf, meta, fmeta, stats, vmx, (it == NITER - 1) ? 1 : 0);
    }
    k_fin<<<dim3(BPTF, cnt), 256, 0, stream>>>(Kbuf,
        wbuf + (size_t)NITER * TSG * WSTR, ubuf, meta, fmeta, stats, vmx, tsacc, ts0);
  }
  k_out<<<1, 64, 0, stream>>>(tsacc, (float*)d_out);
}